// Round 6
// baseline (690.568 us; speedup 1.0000x reference)
//
#include <hip/hip_runtime.h>

typedef unsigned short u16;
typedef _Float16 f16x8 __attribute__((ext_vector_type(8)));
typedef u16 u16x8 __attribute__((ext_vector_type(8)));
typedef float floatx4 __attribute__((ext_vector_type(4)));

#define DEV __device__ __forceinline__

DEV u16 f2h(float f) {
  _Float16 h = (_Float16)f;  // RNE
  return __builtin_bit_cast(u16, h);
}

typedef __attribute__((address_space(3))) void lds_void_t;
typedef const __attribute__((address_space(1))) void gbl_void_t;

DEV void async16(const void* g, void* l) {
  __builtin_amdgcn_global_load_lds((gbl_void_t*)g, (lds_void_t*)l, 16, 0, 0);
}

template <int N>
DEV void wait_vm() {
  static_assert(N == 0 || N == 2 || N == 3 || N == 4 || N == 6 || N == 8 ||
                    N == 9 || N == 12,
                "add vmcnt literal");
  if constexpr (N == 0) asm volatile("s_waitcnt vmcnt(0)" ::: "memory");
  else if constexpr (N == 2) asm volatile("s_waitcnt vmcnt(2)" ::: "memory");
  else if constexpr (N == 3) asm volatile("s_waitcnt vmcnt(3)" ::: "memory");
  else if constexpr (N == 4) asm volatile("s_waitcnt vmcnt(4)" ::: "memory");
  else if constexpr (N == 6) asm volatile("s_waitcnt vmcnt(6)" ::: "memory");
  else if constexpr (N == 8) asm volatile("s_waitcnt vmcnt(8)" ::: "memory");
  else if constexpr (N == 9) asm volatile("s_waitcnt vmcnt(9)" ::: "memory");
  else if constexpr (N == 12) asm volatile("s_waitcnt vmcnt(12)" ::: "memory");
}

// ---------------- fp32 -> fp16 convert ----------------

__global__ __launch_bounds__(256) void k_cvt16(const float* __restrict__ x,
                                               u16* __restrict__ o, int n4) {
  int i = blockIdx.x * 256 + threadIdx.x;
  if (i >= n4) return;
  float4 v = ((const float4*)x)[i];
  *(ushort4*)&o[4 * (size_t)i] =
      make_ushort4(f2h(v.x), f2h(v.y), f2h(v.z), f2h(v.w));
}

// ---------------- reduce 4 fp32 partials -> fp16 ----------------

__global__ __launch_bounds__(256) void k_red4(const float* __restrict__ p,
                                              size_t pstride,
                                              u16* __restrict__ o, int n4) {
  int i = blockIdx.x * 256 + threadIdx.x;
  if (i >= n4) return;
  float4 a = ((const float4*)p)[i];
  float4 b = ((const float4*)(p + pstride))[i];
  float4 c = ((const float4*)(p + 2 * pstride))[i];
  float4 d = ((const float4*)(p + 3 * pstride))[i];
  *(ushort4*)&o[4 * (size_t)i] =
      make_ushort4(f2h((a.x + b.x) + (c.x + d.x)),
                   f2h((a.y + b.y) + (c.y + d.y)),
                   f2h((a.z + b.z) + (c.z + d.z)),
                   f2h((a.w + b.w) + (c.w + d.w)));
}

// ---------------- 16-bit transpose (R x C -> C x R) ----------------

__global__ __launch_bounds__(256) void k_transpose(const u16* __restrict__ in,
                                                   u16* __restrict__ out,
                                                   int R, int C) {
  __shared__ u16 T[64][72];
  int m0 = blockIdx.x * 64;
  int n0 = blockIdx.y * 64;
  int t = threadIdx.x;
#pragma unroll
  for (int i = 0; i < 2; ++i) {
    int lin = i * 2048 + t * 8;
    int r = lin >> 6, c = lin & 63;
    u16x8 d = *(const u16x8*)&in[(size_t)(m0 + r) * C + n0 + c];
#pragma unroll
    for (int j = 0; j < 8; ++j) T[r][c + j] = d[j];
  }
  __syncthreads();
#pragma unroll
  for (int i = 0; i < 2; ++i) {
    int lin = i * 2048 + t * 8;
    int r = lin >> 6, c = lin & 63;
    u16x8 d;
#pragma unroll
    for (int j = 0; j < 8; ++j) d[j] = T[c + j][r];
    *(u16x8*)&out[(size_t)(n0 + r) * R + m0 + c] = d;
  }
}

// ---------------- in-place row softmax over 8192 cols (+opt fp16 copy) ----

template <bool WRITEP>
__global__ __launch_bounds__(256) void k_softmax(float* __restrict__ W,
                                                 u16* __restrict__ P) {
  const size_t row = blockIdx.x;
  float4* pv = (float4*)(W + row * 8192);
  const int t = threadIdx.x;
  const int w = t >> 6, l = t & 63;
  float4 v[8];
#pragma unroll
  for (int i = 0; i < 8; ++i) v[i] = pv[i * 256 + t];
  float m = -1e30f;
#pragma unroll
  for (int i = 0; i < 8; ++i)
    m = fmaxf(m, fmaxf(fmaxf(v[i].x, v[i].y), fmaxf(v[i].z, v[i].w)));
#pragma unroll
  for (int o = 32; o >= 1; o >>= 1) m = fmaxf(m, __shfl_xor(m, o, 64));
  __shared__ float redm[4];
  __shared__ float reds[4];
  if (l == 0) redm[w] = m;
  __syncthreads();
  m = fmaxf(fmaxf(redm[0], redm[1]), fmaxf(redm[2], redm[3]));
  float s = 0.f;
#pragma unroll
  for (int i = 0; i < 8; ++i) {
    v[i].x = __expf(v[i].x - m); s += v[i].x;
    v[i].y = __expf(v[i].y - m); s += v[i].y;
    v[i].z = __expf(v[i].z - m); s += v[i].z;
    v[i].w = __expf(v[i].w - m); s += v[i].w;
  }
#pragma unroll
  for (int o = 32; o >= 1; o >>= 1) s += __shfl_xor(s, o, 64);
  if (l == 0) reds[w] = s;
  __syncthreads();
  s = (reds[0] + reds[1]) + (reds[2] + reds[3]);
  float inv = 1.0f / s;
#pragma unroll
  for (int i = 0; i < 8; ++i) {
    v[i].x *= inv; v[i].y *= inv; v[i].z *= inv; v[i].w *= inv;
    pv[i * 256 + t] = v[i];
    if constexpr (WRITEP) {
      *(ushort4*)&P[row * 8192 + (size_t)(i * 256 + t) * 4] =
          make_ushort4(f2h(v[i].x), f2h(v[i].y), f2h(v[i].z), f2h(v[i].w));
    }
  }
}

// ---------------- GEMM: C[M,N] = A[M,K] * B[N,K]^T (+bias), fp16 ----------
// 128xBN tile, 4 waves (2x2), mfma_f32_16x16x32_f16, BK=32.
// LDS: [row][32] u16 with the four 16B col-slots XOR-swizzled by (row>>1)&3
// -> conflict-free ds_read_b128 (verified: conflicts 1.26e7 -> 0).
// Depth-2 circular pipeline (3 buffers). blockIdx.z = split-K chunk.
// AF32: A fp32 converted while staging (fallback). OMODE: 0=f32, 1=fp16.

template <int BN, bool AF32, int OMODE, bool BIAS, int MINW>
__global__ __launch_bounds__(256, MINW)
void k_gemm(const void* A_, const u16* __restrict__ Bh,
            const float* __restrict__ bias, void* C_, int K, int lda, int ldb,
            int ldc, size_t zstride) {
  constexpr int NT = BN / 32;      // wave col-tiles (4 or 2)
  constexpr int BCHW = BN / 64;    // B 16-row chunks per wave (2 or 1)
  constexpr int D = 2;             // prefetch depth
  constexpr int BC = AF32 ? 1 : (D + 1);   // LDS buffers
  constexpr int LPI = 2 + BCHW;            // async loads / iter / wave
  __shared__ alignas(16) u16 Ash[BC][128 * 32];
  __shared__ alignas(16) u16 Bsh[BC][BN * 32];

  const int m0 = blockIdx.x * 128;
  const int n0 = blockIdx.y * BN;
  const int kz = blockIdx.z * K;   // split-K column base
  const int tid = threadIdx.x;
  const int w = tid >> 6;
  const int l = tid & 63;
  const int lr = l & 15;
  const int lq = l >> 4;
  const int wr = (w >> 1) * 64;
  const int wc = (w & 1) * (BN / 2);
  const int srow = l >> 2;       // 0..15 within a 16-row chunk
  const int scolsw = ((l & 3) ^ ((l >> 3) & 3)) * 8;
  const int sw8 = (lq ^ ((lr >> 1) & 3)) * 8;

  const u16* Ah = (const u16*)A_;
  const float* Af = (const float*)A_;

  floatx4 acc[4][NT] = {};

  if constexpr (!AF32) {
    const int nIter = K / 32;
    auto STAGE = [&](int t, int b) {
      const int k0 = kz + (t < nIter ? t : nIter - 1) * 32;
#pragma unroll
      for (int i = 0; i < 2; ++i) {
        int c = w * 2 + i;
        int row = c * 16 + srow;
        async16(Ah + (size_t)(m0 + row) * lda + k0 + scolsw, &Ash[b][c * 512]);
      }
#pragma unroll
      for (int i = 0; i < BCHW; ++i) {
        int c = w * BCHW + i;
        int row = c * 16 + srow;
        async16(Bh + (size_t)(n0 + row) * ldb + k0 + scolsw, &Bsh[b][c * 512]);
      }
    };

#pragma unroll
    for (int t = 0; t < D; ++t) STAGE(t, t);  // prologue: slots 0..D-1

    int bcon = 0;       // consume slot (iter t)
    int bpro = D % BC;  // produce slot (iter t+D)
    for (int t = 0; t < nIter; ++t) {
      wait_vm<LPI * (D - 1)>();
      __builtin_amdgcn_s_barrier();
      STAGE(t + D, bpro);

      f16x8 fa[4], fb[NT];
#pragma unroll
      for (int x = 0; x < 4; ++x)
        fa[x] = *(const f16x8*)&Ash[bcon][(wr + x * 16 + lr) * 32 + sw8];
#pragma unroll
      for (int x = 0; x < NT; ++x)
        fb[x] = *(const f16x8*)&Bsh[bcon][(wc + x * 16 + lr) * 32 + sw8];
#pragma unroll
      for (int mt = 0; mt < 4; ++mt)
#pragma unroll
        for (int nt = 0; nt < NT; ++nt)
          acc[mt][nt] = __builtin_amdgcn_mfma_f32_16x16x32_f16(
              fa[mt], fb[nt], acc[mt][nt], 0, 0, 0);

      if (++bcon == BC) bcon = 0;
      if (++bpro == BC) bpro = 0;
    }
  } else {
    for (int k0 = 0; k0 < K; k0 += 32) {
      __syncthreads();
#pragma unroll
      for (int i = 0; i < 2; ++i) {
        int lin = i * 2048 + tid * 8;
        int row = lin >> 5, col = lin & 31;
        const float* g = Af + (size_t)(m0 + row) * lda + k0 + col;
        float4 u0 = *(const float4*)g;
        float4 u1 = *(const float4*)(g + 4);
        u16x8 tv;
        tv[0] = f2h(u0.x); tv[1] = f2h(u0.y); tv[2] = f2h(u0.z); tv[3] = f2h(u0.w);
        tv[4] = f2h(u1.x); tv[5] = f2h(u1.y); tv[6] = f2h(u1.z); tv[7] = f2h(u1.w);
        int slot = (col >> 3) ^ ((row >> 1) & 3);
        *(u16x8*)&Ash[0][row * 32 + slot * 8] = tv;
      }
#pragma unroll
      for (int i = 0; i < BCHW; ++i) {
        int c = w * BCHW + i;
        int row = c * 16 + srow;
        async16(Bh + (size_t)(n0 + row) * ldb + k0 + scolsw, &Bsh[0][c * 512]);
      }
      __syncthreads();

      f16x8 fa[4], fb[NT];
#pragma unroll
      for (int x = 0; x < 4; ++x)
        fa[x] = *(const f16x8*)&Ash[0][(wr + x * 16 + lr) * 32 + sw8];
#pragma unroll
      for (int x = 0; x < NT; ++x)
        fb[x] = *(const f16x8*)&Bsh[0][(wc + x * 16 + lr) * 32 + sw8];
#pragma unroll
      for (int mt = 0; mt < 4; ++mt)
#pragma unroll
        for (int nt = 0; nt < NT; ++nt)
          acc[mt][nt] = __builtin_amdgcn_mfma_f32_16x16x32_f16(
              fa[mt], fb[nt], acc[mt][nt], 0, 0, 0);
    }
  }

  float bv[NT];
#pragma unroll
  for (int nt = 0; nt < NT; ++nt)
    bv[nt] = BIAS ? bias[n0 + wc + nt * 16 + lr] : 0.f;
#pragma unroll
  for (int mt = 0; mt < 4; ++mt)
#pragma unroll
    for (int nt = 0; nt < NT; ++nt)
#pragma unroll
      for (int r = 0; r < 4; ++r) {
        float x = acc[mt][nt][r] + bv[nt];
        int row = m0 + wr + mt * 16 + lq * 4 + r;
        int col = n0 + wc + nt * 16 + lr;
        size_t idx = (size_t)row * ldc + col + blockIdx.z * zstride;
        if constexpr (OMODE == 0) {
          ((float*)C_)[idx] = x;
        } else {
          ((u16*)C_)[idx] = f2h(x);
        }
      }
}

// ---------------- big GEMM: 256x256 tile, fp32 out, 1024 threads ---------
// 16 waves (4x4), wave-tile 64x64: 16 MFMA + 8 ds_read/iter. Delivered
// bytes minimized: QK 1 GB -> 512 MB, AV 768 -> 512 MB. LDS 96 KB (D=2,
// 3 buffers) -> 1 block/CU but 4 waves/SIMD TLP. VGPR budget ~116 <= 128
// (4 waves/SIMD cap). Same verified swizzle. blockIdx.z = split-K chunk.

__global__ __launch_bounds__(1024, 4)
void k_gemm_big(const u16* __restrict__ Ah, const u16* __restrict__ Bh,
                float* __restrict__ C_, int K, int lda, int ldb, int ldc,
                size_t zstride) {
  constexpr int D = 2;
  constexpr int BC = D + 1;
  constexpr int LPI = 2;  // 1 A + 1 B async load / iter / lane
  __shared__ alignas(16) u16 Ash[BC][256 * 32];
  __shared__ alignas(16) u16 Bsh[BC][256 * 32];

  const int m0 = blockIdx.x * 256;
  const int n0 = blockIdx.y * 256;
  const int kz = blockIdx.z * K;
  const int tid = threadIdx.x;
  const int w = tid >> 6;       // 0..15
  const int l = tid & 63;
  const int lr = l & 15;
  const int lq = l >> 4;
  const int wrow = (w >> 2) * 64;   // 4 row-waves
  const int wcol = (w & 3) * 64;    // 4 col-waves
  const int srow = l >> 2;          // 0..15
  const int scolsw = ((l & 3) ^ ((l >> 3) & 3)) * 8;
  const int sw8 = (lq ^ ((lr >> 1) & 3)) * 8;

  floatx4 acc[4][4] = {};

  const int nIter = K / 32;
  auto STAGE = [&](int t, int b) {
    const int k0 = kz + (t < nIter ? t : nIter - 1) * 32;
    // A: 256 rows = 16 waves x 16-row chunk, 1 load/lane
    async16(Ah + (size_t)(m0 + w * 16 + srow) * lda + k0 + scolsw,
            &Ash[b][w * 512]);
    // B: 256 rows = 16 waves x 16-row chunk, 1 load/lane
    async16(Bh + (size_t)(n0 + w * 16 + srow) * ldb + k0 + scolsw,
            &Bsh[b][w * 512]);
  };

#pragma unroll
  for (int t = 0; t < D; ++t) STAGE(t, t);

  int bcon = 0;
  int bpro = D % BC;
  for (int t = 0; t < nIter; ++t) {
    wait_vm<LPI * (D - 1)>();
    __builtin_amdgcn_s_barrier();
    STAGE(t + D, bpro);

    f16x8 fa[4], fb[4];
#pragma unroll
    for (int x = 0; x < 4; ++x)
      fa[x] = *(const f16x8*)&Ash[bcon][(wrow + x * 16 + lr) * 32 + sw8];
#pragma unroll
    for (int x = 0; x < 4; ++x)
      fb[x] = *(const f16x8*)&Bsh[bcon][(wcol + x * 16 + lr) * 32 + sw8];
#pragma unroll
    for (int mt = 0; mt < 4; ++mt)
#pragma unroll
      for (int nt = 0; nt < 4; ++nt)
        acc[mt][nt] = __builtin_amdgcn_mfma_f32_16x16x32_f16(
            fa[mt], fb[nt], acc[mt][nt], 0, 0, 0);

    if (++bcon == BC) bcon = 0;
    if (++bpro == BC) bpro = 0;
  }

#pragma unroll
  for (int mt = 0; mt < 4; ++mt)
#pragma unroll
    for (int nt = 0; nt < 4; ++nt)
#pragma unroll
      for (int r = 0; r < 4; ++r) {
        int row = m0 + wrow + mt * 16 + lq * 4 + r;
        int col = n0 + wcol + nt * 16 + lr;
        C_[(size_t)row * ldc + col + blockIdx.z * zstride] = acc[mt][nt][r];
      }
}

// ---------------- launch ----------------

extern "C" void kernel_launch(void* const* d_in, const int* in_sizes, int n_in,
                              void* d_out, int out_size, void* d_ws,
                              size_t ws_size, hipStream_t stream) {
  constexpr int N = 8192, H = 512;
  const float* q   = (const float*)d_in[0];
  const float* kin = (const float*)d_in[1];
  const float* v   = (const float*)d_in[2];
  const float* Wq  = (const float*)d_in[3];
  const float* bq  = (const float*)d_in[4];
  const float* Wk  = (const float*)d_in[5];
  const float* bk  = (const float*)d_in[6];
  const float* Wv  = (const float*)d_in[7];
  const float* bv  = (const float*)d_in[8];
  const float* Wo  = (const float*)d_in[9];
  const float* bo  = (const float*)d_in[10];
  float* out  = (float*)d_out;
  float* norm = out + (size_t)N * H;  // [N,N] normalized region

  char* ws = (char*)d_ws;
  const size_t MB = 1024 * 1024;
  u16* xh   = (u16*)(ws + 0 * MB);    // 8 MB input fp16 (q/k/v serially)
  u16* wb   = (u16*)(ws + 8 * MB);    // 0.5 MB weight fp16
  u16* qp   = (u16*)(ws + 9 * MB);    // 8 MB
  u16* kp   = (u16*)(ws + 17 * MB);   // 8 MB
  u16* vp   = (u16*)(ws + 25 * MB);   // 8 MB (reused as out0 after transpose)
  u16* vpT  = (u16*)(ws + 33 * MB);   // 8 MB [H][N]
  u16* Pf   = (u16*)(ws + 41 * MB);   // 128 MB fp16 probabilities
  float* pS = (float*)(ws + 169 * MB);  // 64 MB split-K fp32 partials
  u16* out0 = vp;

  const bool usePf    = ws_size >= 169 * MB;
  const bool useSplit = ws_size >= 233 * MB;

  dim3 blk(256);

  // q projection
  k_cvt16<<<4096, blk, 0, stream>>>(q, xh, (N * H) / 4);
  k_cvt16<<<256, blk, 0, stream>>>(Wq, wb, (H * H) / 4);
  k_gemm<64, false, 1, true, 2><<<dim3(64, 8), blk, 0, stream>>>(
      xh, wb, bq, qp, H, H, H, H, 0);

  // k projection
  k_cvt16<<<4096, blk, 0, stream>>>(kin, xh, (N * H) / 4);
  k_cvt16<<<256, blk, 0, stream>>>(Wk, wb, (H * H) / 4);
  k_gemm<64, false, 1, true, 2><<<dim3(64, 8), blk, 0, stream>>>(
      xh, wb, bk, kp, H, H, H, H, 0);

  // v projection -> vp, then transpose -> vpT
  k_cvt16<<<4096, blk, 0, stream>>>(v, xh, (N * H) / 4);
  k_cvt16<<<256, blk, 0, stream>>>(Wv, wb, (H * H) / 4);
  k_gemm<64, false, 1, true, 2><<<dim3(64, 8), blk, 0, stream>>>(
      xh, wb, bv, vp, H, H, H, H, 0);
  k_transpose<<<dim3(128, 8), blk, 0, stream>>>(vp, vpT, N, H);

  // logits = qp @ kp^T  (fp32 out into normalized region), 256x256 tiles
  k_gemm_big<<<dim3(32, 32), dim3(1024), 0, stream>>>(
      qp, kp, norm, H, H, H, N, 0);

  // softmax rows in place (+ fp16 copy for the AV GEMM)
  if (usePf)
    k_softmax<true><<<N, blk, 0, stream>>>(norm, Pf);
  else
    k_softmax<false><<<N, blk, 0, stream>>>(norm, nullptr);

  // out0 = normalized @ vp
  if (usePf && useSplit) {
    // 256x256-tile split-K x4 AV (delivered bytes 768 -> 512 MB)
    k_gemm_big<<<dim3(32, 2, 4), dim3(1024), 0, stream>>>(
        Pf, vpT, pS, N / 4, N, N, H, (size_t)N * H);
    k_red4<<<4096, blk, 0, stream>>>(pS, (size_t)N * H, out0, (N * H) / 4);
  } else if (usePf) {
    k_gemm<64, false, 1, false, 4><<<dim3(64, 8), blk, 0, stream>>>(
        Pf, vpT, nullptr, out0, N, N, N, H, 0);
  } else {
    k_gemm<64, true, 1, false, 2><<<dim3(64, 8), blk, 0, stream>>>(
        norm, vpT, nullptr, out0, N, N, N, H, 0);
  }

  // out = out0 @ Wo^T + bo
  k_cvt16<<<256, blk, 0, stream>>>(Wo, wb, (H * H) / 4);
  k_gemm<64, false, 0, true, 2><<<dim3(64, 8), blk, 0, stream>>>(
      out0, wb, bo, out, H, H, H, H, 0);
}

// Round 7
// 659.933 us; speedup vs baseline: 1.0464x; 1.0464x over previous
//
#include <hip/hip_runtime.h>

typedef unsigned short u16;
typedef _Float16 f16x8 __attribute__((ext_vector_type(8)));
typedef u16 u16x8 __attribute__((ext_vector_type(8)));
typedef float floatx4 __attribute__((ext_vector_type(4)));

#define DEV __device__ __forceinline__

DEV u16 f2h(float f) {
  _Float16 h = (_Float16)f;  // RNE
  return __builtin_bit_cast(u16, h);
}

typedef __attribute__((address_space(3))) void lds_void_t;
typedef const __attribute__((address_space(1))) void gbl_void_t;

DEV void async16(const void* g, void* l) {
  __builtin_amdgcn_global_load_lds((gbl_void_t*)g, (lds_void_t*)l, 16, 0, 0);
}

template <int N>
DEV void wait_vm() {
  static_assert(N == 0 || N == 2 || N == 3 || N == 4 || N == 6 || N == 8 ||
                    N == 9 || N == 12,
                "add vmcnt literal");
  if constexpr (N == 0) asm volatile("s_waitcnt vmcnt(0)" ::: "memory");
  else if constexpr (N == 2) asm volatile("s_waitcnt vmcnt(2)" ::: "memory");
  else if constexpr (N == 3) asm volatile("s_waitcnt vmcnt(3)" ::: "memory");
  else if constexpr (N == 4) asm volatile("s_waitcnt vmcnt(4)" ::: "memory");
  else if constexpr (N == 6) asm volatile("s_waitcnt vmcnt(6)" ::: "memory");
  else if constexpr (N == 8) asm volatile("s_waitcnt vmcnt(8)" ::: "memory");
  else if constexpr (N == 9) asm volatile("s_waitcnt vmcnt(9)" ::: "memory");
  else if constexpr (N == 12) asm volatile("s_waitcnt vmcnt(12)" ::: "memory");
}

// ---------------- fp32 -> fp16 converts (batched launches) ----------------

// q/k/v inputs in one launch: blockIdx.y selects the input.
__global__ __launch_bounds__(256) void k_cvt3(const float* __restrict__ a,
                                              const float* __restrict__ b,
                                              const float* __restrict__ c,
                                              u16* __restrict__ o, int n4per) {
  int z = blockIdx.y;
  const float* src = (z == 0) ? a : ((z == 1) ? b : c);
  u16* dst = o + (size_t)z * n4per * 4;
  int i = blockIdx.x * 256 + threadIdx.x;
  if (i >= n4per) return;
  float4 v = ((const float4*)src)[i];
  *(ushort4*)&dst[4 * (size_t)i] =
      make_ushort4(f2h(v.x), f2h(v.y), f2h(v.z), f2h(v.w));
}

// all 4 weights in one launch: blockIdx.y selects; Wq/Wk/Wv go contiguous
// into w3, Wo into wo.
__global__ __launch_bounds__(256) void k_cvtw(const float* __restrict__ wq,
                                              const float* __restrict__ wk,
                                              const float* __restrict__ wv,
                                              const float* __restrict__ wo_,
                                              u16* __restrict__ w3,
                                              u16* __restrict__ wo, int n4per) {
  int z = blockIdx.y;
  const float* src = (z == 0) ? wq : ((z == 1) ? wk : ((z == 2) ? wv : wo_));
  u16* dst = (z < 3) ? (w3 + (size_t)z * n4per * 4) : wo;
  int i = blockIdx.x * 256 + threadIdx.x;
  if (i >= n4per) return;
  float4 v = ((const float4*)src)[i];
  *(ushort4*)&dst[4 * (size_t)i] =
      make_ushort4(f2h(v.x), f2h(v.y), f2h(v.z), f2h(v.w));
}

// ---------------- reduce 4 fp32 partials -> fp16 ----------------

__global__ __launch_bounds__(256) void k_red4(const float* __restrict__ p,
                                              size_t pstride,
                                              u16* __restrict__ o, int n4) {
  int i = blockIdx.x * 256 + threadIdx.x;
  if (i >= n4) return;
  float4 a = ((const float4*)p)[i];
  float4 b = ((const float4*)(p + pstride))[i];
  float4 c = ((const float4*)(p + 2 * pstride))[i];
  float4 d = ((const float4*)(p + 3 * pstride))[i];
  *(ushort4*)&o[4 * (size_t)i] =
      make_ushort4(f2h((a.x + b.x) + (c.x + d.x)),
                   f2h((a.y + b.y) + (c.y + d.y)),
                   f2h((a.z + b.z) + (c.z + d.z)),
                   f2h((a.w + b.w) + (c.w + d.w)));
}

// ---------------- 16-bit transpose (R x C -> C x R) ----------------

__global__ __launch_bounds__(256) void k_transpose(const u16* __restrict__ in,
                                                   u16* __restrict__ out,
                                                   int R, int C) {
  __shared__ u16 T[64][72];
  int m0 = blockIdx.x * 64;
  int n0 = blockIdx.y * 64;
  int t = threadIdx.x;
#pragma unroll
  for (int i = 0; i < 2; ++i) {
    int lin = i * 2048 + t * 8;
    int r = lin >> 6, c = lin & 63;
    u16x8 d = *(const u16x8*)&in[(size_t)(m0 + r) * C + n0 + c];
#pragma unroll
    for (int j = 0; j < 8; ++j) T[r][c + j] = d[j];
  }
  __syncthreads();
#pragma unroll
  for (int i = 0; i < 2; ++i) {
    int lin = i * 2048 + t * 8;
    int r = lin >> 6, c = lin & 63;
    u16x8 d;
#pragma unroll
    for (int j = 0; j < 8; ++j) d[j] = T[c + j][r];
    *(u16x8*)&out[(size_t)(n0 + r) * R + m0 + c] = d;
  }
}

// ---------------- in-place row softmax over 8192 cols (+opt fp16 copy) ----

template <bool WRITEP>
__global__ __launch_bounds__(256) void k_softmax(float* __restrict__ W,
                                                 u16* __restrict__ P) {
  const size_t row = blockIdx.x;
  float4* pv = (float4*)(W + row * 8192);
  const int t = threadIdx.x;
  const int w = t >> 6, l = t & 63;
  float4 v[8];
#pragma unroll
  for (int i = 0; i < 8; ++i) v[i] = pv[i * 256 + t];
  float m = -1e30f;
#pragma unroll
  for (int i = 0; i < 8; ++i)
    m = fmaxf(m, fmaxf(fmaxf(v[i].x, v[i].y), fmaxf(v[i].z, v[i].w)));
#pragma unroll
  for (int o = 32; o >= 1; o >>= 1) m = fmaxf(m, __shfl_xor(m, o, 64));
  __shared__ float redm[4];
  __shared__ float reds[4];
  if (l == 0) redm[w] = m;
  __syncthreads();
  m = fmaxf(fmaxf(redm[0], redm[1]), fmaxf(redm[2], redm[3]));
  float s = 0.f;
#pragma unroll
  for (int i = 0; i < 8; ++i) {
    v[i].x = __expf(v[i].x - m); s += v[i].x;
    v[i].y = __expf(v[i].y - m); s += v[i].y;
    v[i].z = __expf(v[i].z - m); s += v[i].z;
    v[i].w = __expf(v[i].w - m); s += v[i].w;
  }
#pragma unroll
  for (int o = 32; o >= 1; o >>= 1) s += __shfl_xor(s, o, 64);
  if (l == 0) reds[w] = s;
  __syncthreads();
  s = (reds[0] + reds[1]) + (reds[2] + reds[3]);
  float inv = 1.0f / s;
#pragma unroll
  for (int i = 0; i < 8; ++i) {
    v[i].x *= inv; v[i].y *= inv; v[i].z *= inv; v[i].w *= inv;
    pv[i * 256 + t] = v[i];
    if constexpr (WRITEP) {
      *(ushort4*)&P[row * 8192 + (size_t)(i * 256 + t) * 4] =
          make_ushort4(f2h(v[i].x), f2h(v[i].y), f2h(v[i].z), f2h(v[i].w));
    }
  }
}

// ---------------- GEMM: C[M,N] = A[M,K] * B[N,K]^T (+bias), fp16 ----------
// 128xBN tile, 4 waves (2x2), mfma_f32_16x16x32_f16, BK=32.
// LDS: [row][32] u16 with the four 16B col-slots XOR-swizzled by (row>>1)&3
// -> conflict-free ds_read_b128 (verified: conflicts 1.26e7 -> 0).
// Depth-2 circular pipeline (3 buffers). blockIdx.z = split-K chunk.
// AF32: A fp32 converted while staging (fallback). OMODE: 0=f32, 1=fp16.

template <int BN, bool AF32, int OMODE, bool BIAS, int MINW>
__global__ __launch_bounds__(256, MINW)
void k_gemm(const void* A_, const u16* __restrict__ Bh,
            const float* __restrict__ bias, void* C_, int K, int lda, int ldb,
            int ldc, size_t zstride) {
  constexpr int NT = BN / 32;      // wave col-tiles (4 or 2)
  constexpr int BCHW = BN / 64;    // B 16-row chunks per wave (2 or 1)
  constexpr int D = 2;             // prefetch depth
  constexpr int BC = AF32 ? 1 : (D + 1);   // LDS buffers
  constexpr int LPI = 2 + BCHW;            // async loads / iter / wave
  __shared__ alignas(16) u16 Ash[BC][128 * 32];
  __shared__ alignas(16) u16 Bsh[BC][BN * 32];

  const int m0 = blockIdx.x * 128;
  const int n0 = blockIdx.y * BN;
  const int kz = blockIdx.z * K;   // split-K column base
  const int tid = threadIdx.x;
  const int w = tid >> 6;
  const int l = tid & 63;
  const int lr = l & 15;
  const int lq = l >> 4;
  const int wr = (w >> 1) * 64;
  const int wc = (w & 1) * (BN / 2);
  const int srow = l >> 2;       // 0..15 within a 16-row chunk
  const int scolsw = ((l & 3) ^ ((l >> 3) & 3)) * 8;
  const int sw8 = (lq ^ ((lr >> 1) & 3)) * 8;

  const u16* Ah = (const u16*)A_;
  const float* Af = (const float*)A_;

  floatx4 acc[4][NT] = {};

  if constexpr (!AF32) {
    const int nIter = K / 32;
    auto STAGE = [&](int t, int b) {
      const int k0 = kz + (t < nIter ? t : nIter - 1) * 32;
#pragma unroll
      for (int i = 0; i < 2; ++i) {
        int c = w * 2 + i;
        int row = c * 16 + srow;
        async16(Ah + (size_t)(m0 + row) * lda + k0 + scolsw, &Ash[b][c * 512]);
      }
#pragma unroll
      for (int i = 0; i < BCHW; ++i) {
        int c = w * BCHW + i;
        int row = c * 16 + srow;
        async16(Bh + (size_t)(n0 + row) * ldb + k0 + scolsw, &Bsh[b][c * 512]);
      }
    };

#pragma unroll
    for (int t = 0; t < D; ++t) STAGE(t, t);  // prologue: slots 0..D-1

    int bcon = 0;       // consume slot (iter t)
    int bpro = D % BC;  // produce slot (iter t+D)
    for (int t = 0; t < nIter; ++t) {
      wait_vm<LPI * (D - 1)>();
      __builtin_amdgcn_s_barrier();
      STAGE(t + D, bpro);

      f16x8 fa[4], fb[NT];
#pragma unroll
      for (int x = 0; x < 4; ++x)
        fa[x] = *(const f16x8*)&Ash[bcon][(wr + x * 16 + lr) * 32 + sw8];
#pragma unroll
      for (int x = 0; x < NT; ++x)
        fb[x] = *(const f16x8*)&Bsh[bcon][(wc + x * 16 + lr) * 32 + sw8];
#pragma unroll
      for (int mt = 0; mt < 4; ++mt)
#pragma unroll
        for (int nt = 0; nt < NT; ++nt)
          acc[mt][nt] = __builtin_amdgcn_mfma_f32_16x16x32_f16(
              fa[mt], fb[nt], acc[mt][nt], 0, 0, 0);

      if (++bcon == BC) bcon = 0;
      if (++bpro == BC) bpro = 0;
    }
  } else {
    for (int k0 = 0; k0 < K; k0 += 32) {
      __syncthreads();
#pragma unroll
      for (int i = 0; i < 2; ++i) {
        int lin = i * 2048 + tid * 8;
        int row = lin >> 5, col = lin & 31;
        const float* g = Af + (size_t)(m0 + row) * lda + k0 + col;
        float4 u0 = *(const float4*)g;
        float4 u1 = *(const float4*)(g + 4);
        u16x8 tv;
        tv[0] = f2h(u0.x); tv[1] = f2h(u0.y); tv[2] = f2h(u0.z); tv[3] = f2h(u0.w);
        tv[4] = f2h(u1.x); tv[5] = f2h(u1.y); tv[6] = f2h(u1.z); tv[7] = f2h(u1.w);
        int slot = (col >> 3) ^ ((row >> 1) & 3);
        *(u16x8*)&Ash[0][row * 32 + slot * 8] = tv;
      }
#pragma unroll
      for (int i = 0; i < BCHW; ++i) {
        int c = w * BCHW + i;
        int row = c * 16 + srow;
        async16(Bh + (size_t)(n0 + row) * ldb + k0 + scolsw, &Bsh[0][c * 512]);
      }
      __syncthreads();

      f16x8 fa[4], fb[NT];
#pragma unroll
      for (int x = 0; x < 4; ++x)
        fa[x] = *(const f16x8*)&Ash[0][(wr + x * 16 + lr) * 32 + sw8];
#pragma unroll
      for (int x = 0; x < NT; ++x)
        fb[x] = *(const f16x8*)&Bsh[0][(wc + x * 16 + lr) * 32 + sw8];
#pragma unroll
      for (int mt = 0; mt < 4; ++mt)
#pragma unroll
        for (int nt = 0; nt < NT; ++nt)
          acc[mt][nt] = __builtin_amdgcn_mfma_f32_16x16x32_f16(
              fa[mt], fb[nt], acc[mt][nt], 0, 0, 0);
    }
  }

  float bv[NT];
#pragma unroll
  for (int nt = 0; nt < NT; ++nt)
    bv[nt] = BIAS ? bias[n0 + wc + nt * 16 + lr] : 0.f;
#pragma unroll
  for (int mt = 0; mt < 4; ++mt)
#pragma unroll
    for (int nt = 0; nt < NT; ++nt)
#pragma unroll
      for (int r = 0; r < 4; ++r) {
        float x = acc[mt][nt][r] + bv[nt];
        int row = m0 + wr + mt * 16 + lq * 4 + r;
        int col = n0 + wc + nt * 16 + lr;
        size_t idx = (size_t)row * ldc + col + blockIdx.z * zstride;
        if constexpr (OMODE == 0) {
          ((float*)C_)[idx] = x;
        } else {
          ((u16*)C_)[idx] = f2h(x);
        }
      }
}

// ---------------- fused q/k/v projection GEMM (blockIdx.z = projection) ----
// Same structure as k_gemm<64, false, 1, true> but z selects the
// (A, W, bias, C) quadruple. One launch replaces three.

struct Bias3 { const float* p[3]; };

__global__ __launch_bounds__(256, 2)
void k_gemm_proj(const u16* __restrict__ A3, const u16* __restrict__ W3,
                 Bias3 b3, u16* __restrict__ C3) {
  constexpr int H = 512;
  constexpr int D = 2, BC = 3, LPI = 3;
  __shared__ alignas(16) u16 Ash[BC][128 * 32];
  __shared__ alignas(16) u16 Bsh[BC][64 * 32];

  const int z = blockIdx.z;
  const u16* Ah = A3 + (size_t)z * 8192 * H;
  const u16* Bh = W3 + (size_t)z * H * H;
  const float* bias = b3.p[z];
  u16* C = C3 + (size_t)z * 8192 * H;

  const int m0 = blockIdx.x * 128;
  const int n0 = blockIdx.y * 64;
  const int tid = threadIdx.x;
  const int w = tid >> 6;
  const int l = tid & 63;
  const int lr = l & 15;
  const int lq = l >> 4;
  const int wr = (w >> 1) * 64;
  const int wc = (w & 1) * 32;
  const int srow = l >> 2;
  const int scolsw = ((l & 3) ^ ((l >> 3) & 3)) * 8;
  const int sw8 = (lq ^ ((lr >> 1) & 3)) * 8;

  floatx4 acc[4][2] = {};

  const int nIter = H / 32;  // 16
  auto STAGE = [&](int t, int b) {
    const int k0 = (t < nIter ? t : nIter - 1) * 32;
#pragma unroll
    for (int i = 0; i < 2; ++i) {
      int c = w * 2 + i;
      int row = c * 16 + srow;
      async16(Ah + (size_t)(m0 + row) * H + k0 + scolsw, &Ash[b][c * 512]);
    }
    {
      int row = w * 16 + srow;
      async16(Bh + (size_t)(n0 + row) * H + k0 + scolsw, &Bsh[b][w * 512]);
    }
  };

#pragma unroll
  for (int t = 0; t < D; ++t) STAGE(t, t);

  int bcon = 0;
  int bpro = D % BC;
  for (int t = 0; t < nIter; ++t) {
    wait_vm<LPI * (D - 1)>();
    __builtin_amdgcn_s_barrier();
    STAGE(t + D, bpro);

    f16x8 fa[4], fb[2];
#pragma unroll
    for (int x = 0; x < 4; ++x)
      fa[x] = *(const f16x8*)&Ash[bcon][(wr + x * 16 + lr) * 32 + sw8];
#pragma unroll
    for (int x = 0; x < 2; ++x)
      fb[x] = *(const f16x8*)&Bsh[bcon][(wc + x * 16 + lr) * 32 + sw8];
#pragma unroll
    for (int mt = 0; mt < 4; ++mt)
#pragma unroll
      for (int nt = 0; nt < 2; ++nt)
        acc[mt][nt] = __builtin_amdgcn_mfma_f32_16x16x32_f16(
            fa[mt], fb[nt], acc[mt][nt], 0, 0, 0);

    if (++bcon == BC) bcon = 0;
    if (++bpro == BC) bpro = 0;
  }

  float bv[2];
#pragma unroll
  for (int nt = 0; nt < 2; ++nt) bv[nt] = bias[n0 + wc + nt * 16 + lr];
#pragma unroll
  for (int mt = 0; mt < 4; ++mt)
#pragma unroll
    for (int nt = 0; nt < 2; ++nt)
#pragma unroll
      for (int r = 0; r < 4; ++r) {
        int row = m0 + wr + mt * 16 + lq * 4 + r;
        int col = n0 + wc + nt * 16 + lr;
        C[(size_t)row * H + col] = f2h(acc[mt][nt][r] + bv[nt]);
      }
}

// ---------------- AV GEMM: 128x256 tile, 512 threads (8 waves, 2x4) ------
// (R5 config: 2 blocks/CU, split-K x4; delivered bytes 768 MB.)

__global__ __launch_bounds__(512, 4)
void k_gemm_av(const u16* __restrict__ Ah, const u16* __restrict__ Bh,
               float* __restrict__ C_, int K, int lda, int ldb, int ldc,
               size_t zstride) {
  constexpr int D = 2;
  constexpr int BC = D + 1;
  constexpr int LPI = 3;  // 1 A + 2 B async loads / iter / lane
  __shared__ alignas(16) u16 Ash[BC][128 * 32];
  __shared__ alignas(16) u16 Bsh[BC][256 * 32];

  const int m0 = blockIdx.x * 128;
  const int n0 = blockIdx.y * 256;
  const int kz = blockIdx.z * K;
  const int tid = threadIdx.x;
  const int w = tid >> 6;      // 0..7
  const int l = tid & 63;
  const int lr = l & 15;
  const int lq = l >> 4;
  const int wr = (w & 1) * 64;        // 2 row-waves
  const int wc = (w >> 1) * 64;       // 4 col-waves
  const int srow = l >> 2;            // 0..15
  const int scolsw = ((l & 3) ^ ((l >> 3) & 3)) * 8;
  const int sw8 = (lq ^ ((lr >> 1) & 3)) * 8;

  floatx4 acc[4][4] = {};

  const int nIter = K / 32;
  auto STAGE = [&](int t, int b) {
    const int k0 = kz + (t < nIter ? t : nIter - 1) * 32;
    {
      int row = w * 16 + srow;
      async16(Ah + (size_t)(m0 + row) * lda + k0 + scolsw, &Ash[b][w * 512]);
    }
#pragma unroll
    for (int i = 0; i < 2; ++i) {
      int c = w * 2 + i;
      int row = c * 16 + srow;
      async16(Bh + (size_t)(n0 + row) * ldb + k0 + scolsw, &Bsh[b][c * 512]);
    }
  };

#pragma unroll
  for (int t = 0; t < D; ++t) STAGE(t, t);

  int bcon = 0;
  int bpro = D % BC;
  for (int t = 0; t < nIter; ++t) {
    wait_vm<LPI * (D - 1)>();
    __builtin_amdgcn_s_barrier();
    STAGE(t + D, bpro);

    f16x8 fa[4], fb[4];
#pragma unroll
    for (int x = 0; x < 4; ++x)
      fa[x] = *(const f16x8*)&Ash[bcon][(wr + x * 16 + lr) * 32 + sw8];
#pragma unroll
    for (int x = 0; x < 4; ++x)
      fb[x] = *(const f16x8*)&Bsh[bcon][(wc + x * 16 + lr) * 32 + sw8];
#pragma unroll
    for (int mt = 0; mt < 4; ++mt)
#pragma unroll
      for (int nt = 0; nt < 4; ++nt)
        acc[mt][nt] = __builtin_amdgcn_mfma_f32_16x16x32_f16(
            fa[mt], fb[nt], acc[mt][nt], 0, 0, 0);

    if (++bcon == BC) bcon = 0;
    if (++bpro == BC) bpro = 0;
  }

#pragma unroll
  for (int mt = 0; mt < 4; ++mt)
#pragma unroll
    for (int nt = 0; nt < 4; ++nt)
#pragma unroll
      for (int r = 0; r < 4; ++r) {
        int row = m0 + wr + mt * 16 + lq * 4 + r;
        int col = n0 + wc + nt * 16 + lr;
        C_[(size_t)row * ldc + col + blockIdx.z * zstride] = acc[mt][nt][r];
      }
}

// ---------------- launch ----------------

extern "C" void kernel_launch(void* const* d_in, const int* in_sizes, int n_in,
                              void* d_out, int out_size, void* d_ws,
                              size_t ws_size, hipStream_t stream) {
  constexpr int N = 8192, H = 512;
  const float* q   = (const float*)d_in[0];
  const float* kin = (const float*)d_in[1];
  const float* v   = (const float*)d_in[2];
  const float* Wq  = (const float*)d_in[3];
  const float* bq  = (const float*)d_in[4];
  const float* Wk  = (const float*)d_in[5];
  const float* bk  = (const float*)d_in[6];
  const float* Wv  = (const float*)d_in[7];
  const float* bv  = (const float*)d_in[8];
  const float* Wo  = (const float*)d_in[9];
  const float* bo  = (const float*)d_in[10];
  float* out  = (float*)d_out;
  float* norm = out + (size_t)N * H;  // [N,N] normalized region

  // Workspace layout (210 MB peak; lifetimes verified):
  //   [0, 24)    xh3   fp16 [3N][H] inputs  (dead after proj)
  //   [24, 48)   qkv   fp16 [3N][H] outputs (qp 24-32, kp 32-40, vp 40-48;
  //                     dead after QK / transpose)
  //   [0, 64)    pS    fp32 split-K partials (written by AV — reuses the
  //                     dead xh3/qkv region)
  //   [64, 72)   vpT   fp16 [H][N]           (live through AV)
  //   [72, 73.5) wb3   fp16 [3][H][H]
  //   [73.5, 74) wbo   fp16 [H][H]
  //   [74, 82)   out0  fp16 [N][H]
  //   [82, 210)  Pf    fp16 [N][N]           (live through AV)
  char* ws = (char*)d_ws;
  const size_t MB = 1024 * 1024;
  u16* xh3   = (u16*)(ws + 0 * MB);
  u16* qkv   = (u16*)(ws + 24 * MB);
  float* pS  = (float*)(ws + 0 * MB);
  u16* vpT   = (u16*)(ws + 64 * MB);
  u16* wb3   = (u16*)(ws + 72 * MB);
  u16* wbo   = (u16*)(ws + 72 * MB + 3 * (size_t)H * H * 2);
  u16* out0  = (u16*)(ws + 74 * MB);
  u16* Pf    = (u16*)(ws + 82 * MB);

  u16* qp = qkv;
  u16* kp = qkv + (size_t)N * H;
  u16* vp = qkv + 2 * (size_t)N * H;

  const bool usePf = ws_size >= 210 * MB;

  dim3 blk(256);

  // converts: 2 launches total
  k_cvt3<<<dim3(4096, 3), blk, 0, stream>>>(q, kin, v, xh3, (N * H) / 4);
  k_cvtw<<<dim3(256, 4), blk, 0, stream>>>(Wq, Wk, Wv, Wo, wb3, wbo,
                                           (H * H) / 4);

  // q/k/v projections: 1 launch
  Bias3 b3; b3.p[0] = bq; b3.p[1] = bk; b3.p[2] = bv;
  k_gemm_proj<<<dim3(64, 8, 3), blk, 0, stream>>>(xh3, wb3, b3, qkv);

  // v transpose
  k_transpose<<<dim3(128, 8), blk, 0, stream>>>(vp, vpT, N, H);

  // logits = qp @ kp^T (fp32 into normalized region), 128x128 tiles (R5)
  k_gemm<128, false, 0, false, 3><<<dim3(64, 64), blk, 0, stream>>>(
      qp, kp, nullptr, norm, H, H, H, N, 0);

  // softmax rows in place (+ fp16 copy for the AV GEMM)
  if (usePf)
    k_softmax<true><<<N, blk, 0, stream>>>(norm, Pf);
  else
    k_softmax<false><<<N, blk, 0, stream>>>(norm, nullptr);

  // out0 = normalized @ vp
  if (usePf) {
    // 128x256-tile split-K x4 AV (R5 config)
    k_gemm_av<<<dim3(64, 2, 4), dim3(512), 0, stream>>>(
        Pf, vpT, pS, N / 4, N, N, H, (size_t)N * H);
    k_red4<<<4096, blk, 0, stream>>>(pS, (size_t)N * H, out0, (N * H) / 4);
  } else {
    k_gemm<64, true, 1, false, 2><<<dim3(64, 8), blk, 0, stream>>>(
        norm, vpT, nullptr, out0, N, N, N, H, 0);
  }

  // out = out0 @ Wo^T + bo
  k_gemm<64, false, 0, true, 2><<<dim3(64, 8), blk, 0, stream>>>(
      out0, wbo, bo, out, H, H, H, H, 0);
}